// Round 5
// baseline (3309.552 us; speedup 1.0000x reference)
//
#include <hip/hip_runtime.h>
#include <stdint.h>

#define T_STEPS 128
#define BATCH   256

typedef __attribute__((ext_vector_type(8))) short bfrag8;   // 8 x bf16
typedef __attribute__((ext_vector_type(4))) float f32x4;

// ---------------- LDS layout (persistent kernel) ----------------
#define L_WIH0 0
#define L_WHH0 16640
#define L_WC1  33280
#define L_WHH1 49920
#define L_W2   66560
#define L_WOUT 70720
#define L_STG_B 149760
#define L_C0_B  158208
#define L_C1_B  160256
#define L_B1_B  162304
#define L_B2_B  162432
#define SMEM_BYTES 162464

static __device__ __forceinline__ unsigned short f2bf(float f){
  union { float f; unsigned u; } v; v.f = f;
  return (unsigned short)((v.u + 0x7FFFu + ((v.u >> 16) & 1u)) >> 16);  // RNE
}
static __device__ __forceinline__ float sigm(float x){
  return 1.f / (1.f + __expf(-x));
}
static __device__ __forceinline__ float tanh_(float x){
  x = fminf(15.f, fmaxf(-15.f, x));
  float e = __expf(2.f * x);
  return 1.f - 2.f / (e + 1.f);
}
static __device__ __forceinline__ f32x4 mfma16(bfrag8 a, bfrag8 b, f32x4 c){
  return __builtin_amdgcn_mfma_f32_16x16x32_bf16(a, b, c, 0, 0, 0);
}

// Coherence-point fragment load: two relaxed AGENT-scope 64-bit atomic loads.
// This is the SAME primitive class as the (proven) flag spins — the compiler
// emits loads that bypass stale L1/L2 and read the device coherence point.
// No inline asm, no acquire fence (no full-L2 invalidate) needed.
static __device__ __forceinline__ bfrag8 load_mall16(const unsigned short* p){
  union { unsigned long long u[2]; bfrag8 f; } cv;
  cv.u[0] = __hip_atomic_load((const unsigned long long*)p,
                              __ATOMIC_RELAXED, __HIP_MEMORY_SCOPE_AGENT);
  cv.u[1] = __hip_atomic_load((const unsigned long long*)(p + 4),
                              __ATOMIC_RELAXED, __HIP_MEMORY_SCOPE_AGENT);
  return cv.f;
}

// ---------------- prep kernels (proven, verbatim) ----------------
__global__ void cast_f32_bf16(const float* __restrict__ in, unsigned short* __restrict__ out, int n4){
  int i = blockIdx.x * blockDim.x + threadIdx.x;
  if (i < n4){
    float4 v = ((const float4*)in)[i];
    ushort4 o;
    o.x = f2bf(v.x); o.y = f2bf(v.y); o.z = f2bf(v.z); o.w = f2bf(v.w);
    ((ushort4*)out)[i] = o;
  }
}

__global__ void __launch_bounds__(256) gemm_combo(const float* __restrict__ A, const float* __restrict__ B,
                                                  unsigned short* __restrict__ C, int M, int N, int K){
  __shared__ float As[64][17];
  __shared__ float Bs[16][68];
  int col0 = blockIdx.x * 64;
  int row0 = blockIdx.y * 64;
  int tid = threadIdx.x;
  int tx = tid & 15, ty = tid >> 4;
  float acc[4][4] = {};
  for (int kp = 0; kp < K; kp += 16){
    for (int i = tid; i < 64*16; i += 256){
      int r = i >> 4, c = i & 15;
      As[r][c] = A[(size_t)(row0 + r) * K + kp + c];
    }
    for (int i = tid; i < 16*64; i += 256){
      int r = i >> 6, c = i & 63;
      Bs[r][c] = B[(size_t)(kp + r) * N + col0 + c];
    }
    __syncthreads();
    #pragma unroll
    for (int kk = 0; kk < 16; kk++){
      float a[4], b[4];
      #pragma unroll
      for (int i = 0; i < 4; i++) a[i] = As[ty*4 + i][kk];
      #pragma unroll
      for (int j = 0; j < 4; j++) b[j] = Bs[kk][tx*4 + j];
      #pragma unroll
      for (int i = 0; i < 4; i++)
        #pragma unroll
        for (int j = 0; j < 4; j++) acc[i][j] += a[i] * b[j];
    }
    __syncthreads();
  }
  for (int i = 0; i < 4; i++)
    for (int j = 0; j < 4; j++)
      C[(size_t)(row0 + ty*4 + i) * N + col0 + tx*4 + j] = f2bf(acc[i][j]);
}

__global__ void bias_prep(const float* __restrict__ wih1, const float* __restrict__ bih,
                          const float* __restrict__ bhh, const float* __restrict__ wout,
                          const float* __restrict__ bout, float* __restrict__ B1, float* __restrict__ B2){
  int t = blockIdx.x * blockDim.x + threadIdx.x;
  if (t < 2048){
    float s = bih[t] + bhh[t];
    for (int k = 0; k < 512; k++) s += wih1[(size_t)t*512 + k] * bout[k];
    B1[t] = s;
  } else if (t < 2560){
    int n = t - 2048;
    float s = bout[n];
    for (int k = 0; k < 512; k++) s += wout[(size_t)n*512 + k] * bout[k];
    B2[n] = s;
  }
}

// ---------------- persistent recurrence kernel ----------------
// EXACTLY the round-3-proven (3119µs) kernel with ONE surgical change:
// consumer-side h-state reads use relaxed AGENT atomic loads (coherence-point
// reads, same primitive as the proven flag spins) instead of cached loads, and
// the two per-step ACQUIRE fences (full-L2 buffer_inv) are deleted. Producer
// side (cached stores + waitcnt + release-wbl2 + relaxed flag) is unchanged.
// Side benefit: no invalidates -> x tiles stay L2-warm across steps.
__global__ void __launch_bounds__(256, 1) fflstm_persist(
    const unsigned short* __restrict__ xb,     // [T][256][512] bf16
    const unsigned short* __restrict__ wih0g,
    const unsigned short* __restrict__ whh0g,
    const unsigned short* __restrict__ wc1g,   // W_ih1 @ W_out
    const unsigned short* __restrict__ whh1g,
    const unsigned short* __restrict__ w2g,    // W_out @ W_out
    const unsigned short* __restrict__ woutg,
    const float* __restrict__ b1g,
    const float* __restrict__ b2g,
    unsigned short* __restrict__ h0buf,        // [2][256][512] bf16 parity buffers
    unsigned short* __restrict__ h1buf,
    unsigned int* flags1,                      // [256]
    unsigned int* flags2,
    float* __restrict__ out)                   // [T][256][512] fp32
{
  extern __shared__ char smem[];
  unsigned short* wl = (unsigned short*)smem;
  float* stg  = (float*)(smem + L_STG_B);
  float* c0L  = (float*)(smem + L_C0_B);
  float* c1L  = (float*)(smem + L_C1_B);
  float* b1sl = (float*)(smem + L_B1_B);
  float* b2sl = (float*)(smem + L_B2_B);

  const int wg = blockIdx.x;
  const int bg = wg >> 6;        // batch group (64 rows each)
  const int wn = wg & 63;        // column-slice: 8 h-cols, 32 gate-cols
  const int tid = threadIdx.x;
  const int wave = tid >> 6;
  const int lane = tid & 63;
  const int quad = lane >> 4;
  const int l16  = lane & 15;

  // ---- stage weight slices into LDS (rows packed [i(8) f(8) g(8) o(8)]) ----
  {
    const unsigned short* gsrc[4] = { wih0g, whh0g, wc1g, whh1g };
    #pragma unroll
    for (int m = 0; m < 4; m++){
      unsigned short* dst = wl + m * 16640;
      const unsigned short* src = gsrc[m];
      for (int i = tid; i < 32*512; i += 256){
        int s = i >> 9, k = i & 511;
        int gr = ((s >> 3) << 9) + wn*8 + (s & 7);
        dst[s*520 + k] = src[(size_t)gr*512 + k];
      }
    }
    const unsigned short* osrc[2] = { w2g, woutg };
    #pragma unroll
    for (int m = 0; m < 2; m++){
      unsigned short* dst = wl + L_W2 + m * 4160;
      const unsigned short* src = osrc[m];
      for (int i = tid; i < 8*512; i += 256){
        int s = i >> 9, k = i & 511;
        dst[s*520 + k] = src[(size_t)(wn*8 + s)*512 + k];
      }
    }
  }
  if (tid < 32) b1sl[tid] = b1g[((tid >> 3) << 9) + wn*8 + (tid & 7)];
  if (tid < 8)  b2sl[tid] = b2g[wn*8 + tid];
  for (int i = tid; i < 512; i += 256){ c0L[i] = 0.f; c1L[i] = 0.f; }
  __syncthreads();

  const int rowA = bg*64 + wave*16 + l16;   // A-fragment row for this lane
  const int kfo  = quad*8;                  // A/B fragment k offset

#define BF(base, nt, k0) (*(const bfrag8*)&wl[(base) + ((nt)*16 + l16)*520 + (k0) + kfo])

  // prologue: x-part of gates0 for t=0
  f32x4 xacc0 = {0.f,0.f,0.f,0.f}, xacc1 = {0.f,0.f,0.f,0.f};
  {
    const unsigned short* xr = xb + (size_t)rowA*512 + kfo;
    #pragma unroll
    for (int ks = 0; ks < 16; ks++){
      bfrag8 a = *(const bfrag8*)(xr + ks*32);
      xacc0 = mfma16(a, BF(L_WIH0, 0, ks*32), xacc0);
      xacc1 = mfma16(a, BF(L_WIH0, 1, ks*32), xacc1);
    }
  }

  bfrag8 h0f[16], h1f[16];   // register-cached activation fragments
  f32x4 oacc = {0.f,0.f,0.f,0.f};   // loop-carried: out-partial of step t-1
  const int ewr = tid & 63;
  const int ewc = (tid >> 6) * 2;
  const size_t hslice = (size_t)(bg*64)*512 + wn*8;

  for (int t = 0; t <= T_STEPS; t++){
    const int par = t & 1;
    const size_t poff = (size_t)par * (BATCH*512);

    // ===== A: gates0 = xacc + h0(t-1) @ W_hh0 (h0 frags cached in regs) =====
    if (t < T_STEPS){
      f32x4 g0a = xacc0, g0b = xacc1;
      if (t > 0){
        #pragma unroll
        for (int ks = 0; ks < 16; ks++){
          g0a = mfma16(h0f[ks], BF(L_WHH0, 0, ks*32), g0a);
          g0b = mfma16(h0f[ks], BF(L_WHH0, 1, ks*32), g0b);
        }
      }
      {   // stage [64x32] + LSTM elementwise -> h0' (bf16 to global), c0 (LDS)
        const int rb2 = wave*16 + quad*4;
        #pragma unroll
        for (int r = 0; r < 4; r++){
          stg[(rb2+r)*33 + l16]      = g0a[r];
          stg[(rb2+r)*33 + 16 + l16] = g0b[r];
        }
        __syncthreads();
        const float* sr = stg + ewr*33;
        float cA = c0L[ewr*8 + ewc], cB = c0L[ewr*8 + ewc + 1];
        float cnA = sigm(sr[8+ewc])  *cA + sigm(sr[ewc])  *tanh_(sr[16+ewc]);
        float cnB = sigm(sr[8+ewc+1])*cB + sigm(sr[ewc+1])*tanh_(sr[16+ewc+1]);
        c0L[ewr*8 + ewc] = cnA; c0L[ewr*8 + ewc + 1] = cnB;
        float hA = sigm(sr[24+ewc])  *tanh_(cnA);
        float hB = sigm(sr[24+ewc+1])*tanh_(cnB);
        unsigned pk = (unsigned)f2bf(hA) | ((unsigned)f2bf(hB) << 16);
        *(unsigned*)(h0buf + poff + hslice + (size_t)ewr*512 + ewc) = pk;
      }
      __builtin_amdgcn_s_waitcnt(0);
      __syncthreads();
      if (tid == 0){
        __builtin_amdgcn_fence(__ATOMIC_RELEASE, "agent");   // wbl2 only (proven)
        __hip_atomic_store(&flags1[wg], (unsigned)(t+1), __ATOMIC_RELAXED, __HIP_MEMORY_SCOPE_AGENT);
      }
    }

    // ===== F (deferred from step t-1): wait flag2; out(t-1) = oacc + h1'(t-1)@Wout =====
    if (t >= 1){
      if (tid < 64){
        int spins = 0;
        while (__hip_atomic_load(&flags2[bg*64 + tid], __ATOMIC_RELAXED, __HIP_MEMORY_SCOPE_AGENT) < (unsigned)t){
          __builtin_amdgcn_s_sleep(1);
          if (++spins > (1 << 20)) break;
        }
      }
      __syncthreads();                         // all threads gated on the spin
      __builtin_amdgcn_sched_barrier(0);       // no hoisting of loads above spin
      {
        const unsigned short* hr = h1buf + (size_t)((t-1)&1)*(BATCH*512) + (size_t)rowA*512 + kfo;
        #pragma unroll
        for (int ks = 0; ks < 16; ks++){
          h1f[ks] = load_mall16(hr + ks*32);   // coherence-point read; cached for phase B
          oacc = mfma16(h1f[ks], BF(L_WOUT, 0, ks*32), oacc);
        }
      }
      if (l16 < 8){
        size_t ob = (size_t)(t-1)*(BATCH*512) + (size_t)(bg*64 + wave*16 + quad*4)*512 + wn*8 + l16;
        out[ob]        = oacc[0];
        out[ob + 512]  = oacc[1];
        out[ob + 1024] = oacc[2];
        out[ob + 1536] = oacc[3];
      }
    }

    if (t < T_STEPS){
      // ===== B (off critical path): gates1 partial = B1 + h1(t-1) @ W_hh1 =====
      float bbA = b1sl[l16], bbB = b1sl[16 + l16];
      f32x4 g1a = {bbA,bbA,bbA,bbA}, g1b = {bbB,bbB,bbB,bbB};
      if (t > 0){
        #pragma unroll
        for (int ks = 0; ks < 16; ks++){
          g1a = mfma16(h1f[ks], BF(L_WHH1, 0, ks*32), g1a);
          g1b = mfma16(h1f[ks], BF(L_WHH1, 1, ks*32), g1b);
        }
      }
      // ===== C (off critical path): x-part of gates0 for t+1 =====
      if (t < T_STEPS - 1){
        f32x4 z = {0.f,0.f,0.f,0.f};
        xacc0 = z; xacc1 = z;
        const unsigned short* xr = xb + ((size_t)(t+1)*BATCH + rowA)*512 + kfo;
        #pragma unroll
        for (int ks = 0; ks < 16; ks++){
          bfrag8 a = *(const bfrag8*)(xr + ks*32);
          xacc0 = mfma16(a, BF(L_WIH0, 0, ks*32), xacc0);
          xacc1 = mfma16(a, BF(L_WIH0, 1, ks*32), xacc1);
        }
      }
      // ===== wait flag1 (h0' of whole batch-group at MALL) =====
      if (tid < 64){
        int spins = 0;
        while (__hip_atomic_load(&flags1[bg*64 + tid], __ATOMIC_RELAXED, __HIP_MEMORY_SCOPE_AGENT) < (unsigned)(t+1)){
          __builtin_amdgcn_s_sleep(1);
          if (++spins > (1 << 20)) break;   // hang safety
        }
      }
      __syncthreads();
      __builtin_amdgcn_sched_barrier(0);

      // ===== D+E: one pass over h0'(t): gates1 += h0'@Wc1 ; oacc = B2 + h0'@W2 =====
      float bo = (l16 < 8) ? b2sl[l16] : 0.f;
      oacc[0] = bo; oacc[1] = bo; oacc[2] = bo; oacc[3] = bo;
      {
        const unsigned short* hr = h0buf + poff + (size_t)rowA*512 + kfo;
        #pragma unroll
        for (int ks = 0; ks < 16; ks++){
          h0f[ks] = load_mall16(hr + ks*32);   // coherence-point read; cached for next phase A
          g1a  = mfma16(h0f[ks], BF(L_WC1, 0, ks*32), g1a);
          g1b  = mfma16(h0f[ks], BF(L_WC1, 1, ks*32), g1b);
          oacc = mfma16(h0f[ks], BF(L_W2,  0, ks*32), oacc);
        }
      }
      {   // stage + elementwise -> h1', c1
        const int rb2 = wave*16 + quad*4;
        #pragma unroll
        for (int r = 0; r < 4; r++){
          stg[(rb2+r)*33 + l16]      = g1a[r];
          stg[(rb2+r)*33 + 16 + l16] = g1b[r];
        }
        __syncthreads();
        const float* sr = stg + ewr*33;
        float cA = c1L[ewr*8 + ewc], cB = c1L[ewr*8 + ewc + 1];
        float cnA = sigm(sr[8+ewc])  *cA + sigm(sr[ewc])  *tanh_(sr[16+ewc]);
        float cnB = sigm(sr[8+ewc+1])*cB + sigm(sr[ewc+1])*tanh_(sr[16+ewc+1]);
        c1L[ewr*8 + ewc] = cnA; c1L[ewr*8 + ewc + 1] = cnB;
        float hA = sigm(sr[24+ewc])  *tanh_(cnA);
        float hB = sigm(sr[24+ewc+1])*tanh_(cnB);
        unsigned pk = (unsigned)f2bf(hA) | ((unsigned)f2bf(hB) << 16);
        *(unsigned*)(h1buf + poff + hslice + (size_t)ewr*512 + ewc) = pk;
      }
      __builtin_amdgcn_s_waitcnt(0);
      __syncthreads();
      if (tid == 0){
        __builtin_amdgcn_fence(__ATOMIC_RELEASE, "agent");   // wbl2 only (proven)
        __hip_atomic_store(&flags2[wg], (unsigned)(t+1), __ATOMIC_RELAXED, __HIP_MEMORY_SCOPE_AGENT);
      }
    }
  }
#undef BF
}

// ---------------- host (round-3 verbatim) ----------------
extern "C" void kernel_launch(void* const* d_in, const int* in_sizes, int n_in,
                              void* d_out, int out_size, void* d_ws, size_t ws_size,
                              hipStream_t stream){
  (void)in_sizes; (void)n_in; (void)out_size; (void)ws_size;
  const float* x    = (const float*)d_in[0];
  const float* wih0 = (const float*)d_in[1];
  const float* whh0 = (const float*)d_in[2];
  const float* wih1 = (const float*)d_in[3];
  const float* whh1 = (const float*)d_in[4];
  const float* bih1 = (const float*)d_in[5];
  const float* bhh1 = (const float*)d_in[6];
  const float* wout = (const float*)d_in[7];
  const float* bout = (const float*)d_in[8];

  char* ws = (char*)d_ws;
  size_t off = 0;
  auto alloc = [&](size_t bytes){ void* p = ws + off; off += (bytes + 255) & ~(size_t)255; return p; };
  unsigned short* xbf   = (unsigned short*)alloc(33554432);  // x bf16
  unsigned short* wih0b = (unsigned short*)alloc(2097152);
  unsigned short* whh0b = (unsigned short*)alloc(2097152);
  unsigned short* wc1b  = (unsigned short*)alloc(2097152);
  unsigned short* whh1b = (unsigned short*)alloc(2097152);
  unsigned short* w2b   = (unsigned short*)alloc(524288);
  unsigned short* woutb = (unsigned short*)alloc(524288);
  float* b1 = (float*)alloc(8192);
  float* b2 = (float*)alloc(2048);
  unsigned short* h0b = (unsigned short*)alloc(524288);
  unsigned short* h1b = (unsigned short*)alloc(524288);
  unsigned int* flags = (unsigned int*)alloc(2048);

  hipMemsetAsync(flags, 0, 2048, stream);
  cast_f32_bf16<<<16384, 256, 0, stream>>>(x, xbf, 16777216/4);
  cast_f32_bf16<<<1024, 256, 0, stream>>>(wih0, wih0b, 1048576/4);
  cast_f32_bf16<<<1024, 256, 0, stream>>>(whh0, whh0b, 1048576/4);
  cast_f32_bf16<<<1024, 256, 0, stream>>>(whh1, whh1b, 1048576/4);
  cast_f32_bf16<<<256,  256, 0, stream>>>(wout, woutb, 262144/4);
  gemm_combo<<<dim3(8,32), 256, 0, stream>>>(wih1, wout, wc1b, 2048, 512, 512);  // Wc1 = W_ih1 @ W_out
  gemm_combo<<<dim3(8,8),  256, 0, stream>>>(wout, wout, w2b,  512, 512, 512);   // W2  = W_out @ W_out
  bias_prep<<<10, 256, 0, stream>>>(wih1, bih1, bhh1, wout, bout, b1, b2);

  unsigned int* f1p = flags;
  unsigned int* f2p = flags + 256;
  float* outp = (float*)d_out;
  void* kargs[] = {
    (void*)&xbf, (void*)&wih0b, (void*)&whh0b, (void*)&wc1b, (void*)&whh1b,
    (void*)&w2b, (void*)&woutb, (void*)&b1, (void*)&b2,
    (void*)&h0b, (void*)&h1b, (void*)&f1p, (void*)&f2p, (void*)&outp
  };
  hipFuncSetAttribute((const void*)fflstm_persist,
                      hipFuncAttributeMaxDynamicSharedMemorySize, SMEM_BYTES);
  hipLaunchCooperativeKernel((const void*)fflstm_persist, dim3(256), dim3(256),
                             kargs, SMEM_BYTES, stream);
}

// Round 6
// 2946.678 us; speedup vs baseline: 1.1231x; 1.1231x over previous
//
#include <hip/hip_runtime.h>
#include <stdint.h>

#define T_STEPS 128
#define BATCH   256

typedef __attribute__((ext_vector_type(8))) short bfrag8;   // 8 x bf16
typedef __attribute__((ext_vector_type(4))) float f32x4;

// ---------------- LDS layout (persistent kernel) ----------------
#define L_WIH0 0
#define L_WHH0 16640
#define L_WC1  33280
#define L_WHH1 49920
#define L_W2   66560
#define L_WOUT 70720
#define L_STG_B 149760
#define L_C0_B  158208
#define L_C1_B  160256
#define L_B1_B  162304
#define L_B2_B  162432
#define L_NXA_B 162464
#define SMEM_BYTES 162496

static __device__ __forceinline__ unsigned short f2bf(float f){
  union { float f; unsigned u; } v; v.f = f;
  return (unsigned short)((v.u + 0x7FFFu + ((v.u >> 16) & 1u)) >> 16);  // RNE
}
static __device__ __forceinline__ float sigm(float x){
  return 1.f / (1.f + __expf(-x));
}
static __device__ __forceinline__ float tanh_(float x){
  x = fminf(15.f, fmaxf(-15.f, x));
  float e = __expf(2.f * x);
  return 1.f - 2.f / (e + 1.f);
}
static __device__ __forceinline__ f32x4 mfma16(bfrag8 a, bfrag8 b, f32x4 c){
  return __builtin_amdgcn_mfma_f32_16x16x32_bf16(a, b, c, 0, 0, 0);
}

// ---------------- prep kernels (proven, verbatim) ----------------
__global__ void cast_f32_bf16(const float* __restrict__ in, unsigned short* __restrict__ out, int n4){
  int i = blockIdx.x * blockDim.x + threadIdx.x;
  if (i < n4){
    float4 v = ((const float4*)in)[i];
    ushort4 o;
    o.x = f2bf(v.x); o.y = f2bf(v.y); o.z = f2bf(v.z); o.w = f2bf(v.w);
    ((ushort4*)out)[i] = o;
  }
}

__global__ void __launch_bounds__(256) gemm_combo(const float* __restrict__ A, const float* __restrict__ B,
                                                  unsigned short* __restrict__ C, int M, int N, int K){
  __shared__ float As[64][17];
  __shared__ float Bs[16][68];
  int col0 = blockIdx.x * 64;
  int row0 = blockIdx.y * 64;
  int tid = threadIdx.x;
  int tx = tid & 15, ty = tid >> 4;
  float acc[4][4] = {};
  for (int kp = 0; kp < K; kp += 16){
    for (int i = tid; i < 64*16; i += 256){
      int r = i >> 4, c = i & 15;
      As[r][c] = A[(size_t)(row0 + r) * K + kp + c];
    }
    for (int i = tid; i < 16*64; i += 256){
      int r = i >> 6, c = i & 63;
      Bs[r][c] = B[(size_t)(kp + r) * N + col0 + c];
    }
    __syncthreads();
    #pragma unroll
    for (int kk = 0; kk < 16; kk++){
      float a[4], b[4];
      #pragma unroll
      for (int i = 0; i < 4; i++) a[i] = As[ty*4 + i][kk];
      #pragma unroll
      for (int j = 0; j < 4; j++) b[j] = Bs[kk][tx*4 + j];
      #pragma unroll
      for (int i = 0; i < 4; i++)
        #pragma unroll
        for (int j = 0; j < 4; j++) acc[i][j] += a[i] * b[j];
    }
    __syncthreads();
  }
  for (int i = 0; i < 4; i++)
    for (int j = 0; j < 4; j++)
      C[(size_t)(row0 + ty*4 + i) * N + col0 + tx*4 + j] = f2bf(acc[i][j]);
}

__global__ void bias_prep(const float* __restrict__ wih1, const float* __restrict__ bih,
                          const float* __restrict__ bhh, const float* __restrict__ wout,
                          const float* __restrict__ bout, float* __restrict__ B1, float* __restrict__ B2){
  int t = blockIdx.x * blockDim.x + threadIdx.x;
  if (t < 2048){
    float s = bih[t] + bhh[t];
    for (int k = 0; k < 512; k++) s += wih1[(size_t)t*512 + k] * bout[k];
    B1[t] = s;
  } else if (t < 2560){
    int n = t - 2048;
    float s = bout[n];
    for (int k = 0; k < 512; k++) s += wout[(size_t)n*512 + k] * bout[k];
    B2[n] = s;
  }
}

// ---------------- persistent recurrence kernel ----------------
// Base: round-3-proven (2876µs) kernel. ONE change: the per-step publishes no
// longer have EVERY wg issue a release fence (256 buffer_wbl2 per handshake =
// 32 concurrent full-L2 tag-walks per XCD). Instead, wgs arrive at a per-XCD
// election counter (agent atomicAdd, MALL); the LAST arriver on each XCD
// issues ONE release fence (wbl2 flushes the whole shared L2, including peers'
// vmcnt-ack'd dirty lines) and bumps that XCD's flag. Consumers spin on the 8
// XCD flags, then do the round-3-proven per-wg acquire-inv + cached loads.
// XCD identity is read at runtime (s_getreg HW_REG_XCC_ID) and registered at
// init — correctness does not assume any wg->XCD mapping.
__global__ void __launch_bounds__(256, 1) fflstm_persist(
    const unsigned short* __restrict__ xb,     // [T][256][512] bf16
    const unsigned short* __restrict__ wih0g,
    const unsigned short* __restrict__ whh0g,
    const unsigned short* __restrict__ wc1g,   // W_ih1 @ W_out
    const unsigned short* __restrict__ whh1g,
    const unsigned short* __restrict__ w2g,    // W_out @ W_out
    const unsigned short* __restrict__ woutg,
    const float* __restrict__ b1g,
    const float* __restrict__ b2g,
    unsigned short* __restrict__ h0buf,        // [2][256][512] bf16 parity buffers
    unsigned short* __restrict__ h1buf,
    unsigned int* flags1,                      // control block (see layout below)
    unsigned int* flags2,                      // unused
    float* __restrict__ out)                   // [T][256][512] fp32
{
  (void)flags2;
  extern __shared__ char smem[];
  unsigned short* wl = (unsigned short*)smem;
  float* stg  = (float*)(smem + L_STG_B);
  float* c0L  = (float*)(smem + L_C0_B);
  float* c1L  = (float*)(smem + L_C1_B);
  float* b1sl = (float*)(smem + L_B1_B);
  float* b2sl = (float*)(smem + L_B2_B);
  unsigned* nxa = (unsigned*)(smem + L_NXA_B);   // [8] wg count per XCD

  // control block in flags1 (memset 0 by host each launch), 64B-separated:
  unsigned int* cntb  = flags1;        // [8]  election counters (monotonic)
  unsigned int* xflag = flags1 + 16;   // [8]  per-XCD publish flags
  unsigned int* xcnt  = flags1 + 32;   // [8]  registration counts
  unsigned int* gcnt  = flags1 + 48;   // [1]  global registration count

  const int wg = blockIdx.x;
  const int bg = wg >> 6;        // batch group (64 rows each)
  const int wn = wg & 63;        // column-slice: 8 h-cols, 32 gate-cols
  const int tid = threadIdx.x;
  const int wave = tid >> 6;
  const int lane = tid & 63;
  const int quad = lane >> 4;
  const int l16  = lane & 15;

  int myxcd = 0;
  asm volatile("s_getreg_b32 %0, hwreg(HW_REG_XCC_ID)" : "=s"(myxcd));
  myxcd &= 7;

  // ---- stage weight slices into LDS (rows packed [i(8) f(8) g(8) o(8)]) ----
  {
    const unsigned short* gsrc[4] = { wih0g, whh0g, wc1g, whh1g };
    #pragma unroll
    for (int m = 0; m < 4; m++){
      unsigned short* dst = wl + m * 16640;
      const unsigned short* src = gsrc[m];
      for (int i = tid; i < 32*512; i += 256){
        int s = i >> 9, k = i & 511;
        int gr = ((s >> 3) << 9) + wn*8 + (s & 7);
        dst[s*520 + k] = src[(size_t)gr*512 + k];
      }
    }
    const unsigned short* osrc[2] = { w2g, woutg };
    #pragma unroll
    for (int m = 0; m < 2; m++){
      unsigned short* dst = wl + L_W2 + m * 4160;
      const unsigned short* src = osrc[m];
      for (int i = tid; i < 8*512; i += 256){
        int s = i >> 9, k = i & 511;
        dst[s*520 + k] = src[(size_t)(wn*8 + s)*512 + k];
      }
    }
  }
  if (tid < 32) b1sl[tid] = b1g[((tid >> 3) << 9) + wn*8 + (tid & 7)];
  if (tid < 8)  b2sl[tid] = b2g[wn*8 + tid];
  for (int i = tid; i < 512; i += 256){ c0L[i] = 0.f; c1L[i] = 0.f; }

  // ---- one-time XCD registration + global init barrier ----
  if (tid == 0){
    __hip_atomic_fetch_add(&xcnt[myxcd], 1u, __ATOMIC_RELAXED, __HIP_MEMORY_SCOPE_AGENT);
    __hip_atomic_fetch_add(gcnt, 1u, __ATOMIC_RELAXED, __HIP_MEMORY_SCOPE_AGENT);
    int spins = 0;
    while (__hip_atomic_load(gcnt, __ATOMIC_RELAXED, __HIP_MEMORY_SCOPE_AGENT) < 256u){
      __builtin_amdgcn_s_sleep(1);
      if (++spins > (1 << 22)) break;   // hang safety
    }
  }
  __syncthreads();
  if (tid < 8)
    nxa[tid] = __hip_atomic_load(&xcnt[tid], __ATOMIC_RELAXED, __HIP_MEMORY_SCOPE_AGENT);
  __syncthreads();

  const int rowA = bg*64 + wave*16 + l16;   // A-fragment row for this lane
  const int kfo  = quad*8;                  // A/B fragment k offset

#define BF(base, nt, k0) (*(const bfrag8*)&wl[(base) + ((nt)*16 + l16)*520 + (k0) + kfo])

// publish handshake HIDX: drain own stores to L2, arrive at XCD counter; last
// arriver on the XCD issues the single release-wbl2 + flag. (agent atomics are
// MALL-side; fence ordered after the arriving add by vmcnt semantics.)
#define PUBLISH(HIDX)                                                                          \
  do {                                                                                         \
    __builtin_amdgcn_s_waitcnt(0);                                                             \
    __syncthreads();                                                                           \
    if (tid == 0){                                                                             \
      unsigned old = __hip_atomic_fetch_add(&cntb[myxcd], 1u,                                  \
                        __ATOMIC_RELAXED, __HIP_MEMORY_SCOPE_AGENT);                           \
      if (old == (unsigned)(HIDX) * nxa[myxcd] - 1u){                                          \
        __builtin_amdgcn_fence(__ATOMIC_RELEASE, "agent");   /* one wbl2 per XCD */            \
        __hip_atomic_store(&xflag[myxcd], (unsigned)(HIDX),                                    \
                           __ATOMIC_RELAXED, __HIP_MEMORY_SCOPE_AGENT);                        \
      }                                                                                        \
    }                                                                                          \
  } while (0)

// wait handshake HIDX: all 8 XCD flags (skip empty XCDs), then round-3-proven
// per-wg acquire-inv so cached loads below observe MALL-fresh data.
#define WAITX(HIDX)                                                                            \
  do {                                                                                         \
    if (tid < 8){                                                                              \
      int spins = 0;                                                                           \
      while (nxa[tid] != 0 &&                                                                  \
             __hip_atomic_load(&xflag[tid], __ATOMIC_RELAXED, __HIP_MEMORY_SCOPE_AGENT)        \
               < (unsigned)(HIDX)){                                                            \
        __builtin_amdgcn_s_sleep(1);                                                           \
        if (++spins > (1 << 20)) break;                                                        \
      }                                                                                        \
    }                                                                                          \
    if (tid == 0) __builtin_amdgcn_fence(__ATOMIC_ACQUIRE, "agent");   /* inv */               \
    __syncthreads();                                                                           \
  } while (0)

  // prologue: x-part of gates0 for t=0
  f32x4 xacc0 = {0.f,0.f,0.f,0.f}, xacc1 = {0.f,0.f,0.f,0.f};
  {
    const unsigned short* xr = xb + (size_t)rowA*512 + kfo;
    #pragma unroll
    for (int ks = 0; ks < 16; ks++){
      bfrag8 a = *(const bfrag8*)(xr + ks*32);
      xacc0 = mfma16(a, BF(L_WIH0, 0, ks*32), xacc0);
      xacc1 = mfma16(a, BF(L_WIH0, 1, ks*32), xacc1);
    }
  }

  bfrag8 h0f[16], h1f[16];   // register-cached activation fragments
  f32x4 oacc = {0.f,0.f,0.f,0.f};   // loop-carried: out-partial of step t-1
  const int ewr = tid & 63;
  const int ewc = (tid >> 6) * 2;
  const size_t hslice = (size_t)(bg*64)*512 + wn*8;

  for (int t = 0; t <= T_STEPS; t++){
    const int par = t & 1;
    const size_t poff = (size_t)par * (BATCH*512);

    // ===== A: gates0 = xacc + h0(t-1) @ W_hh0 (h0 frags cached in regs) =====
    if (t < T_STEPS){
      f32x4 g0a = xacc0, g0b = xacc1;
      if (t > 0){
        #pragma unroll
        for (int ks = 0; ks < 16; ks++){
          g0a = mfma16(h0f[ks], BF(L_WHH0, 0, ks*32), g0a);
          g0b = mfma16(h0f[ks], BF(L_WHH0, 1, ks*32), g0b);
        }
      }
      {   // stage [64x32] + LSTM elementwise -> h0' (bf16 to global), c0 (LDS)
        const int rb2 = wave*16 + quad*4;
        #pragma unroll
        for (int r = 0; r < 4; r++){
          stg[(rb2+r)*33 + l16]      = g0a[r];
          stg[(rb2+r)*33 + 16 + l16] = g0b[r];
        }
        __syncthreads();
        const float* sr = stg + ewr*33;
        float cA = c0L[ewr*8 + ewc], cB = c0L[ewr*8 + ewc + 1];
        float cnA = sigm(sr[8+ewc])  *cA + sigm(sr[ewc])  *tanh_(sr[16+ewc]);
        float cnB = sigm(sr[8+ewc+1])*cB + sigm(sr[ewc+1])*tanh_(sr[16+ewc+1]);
        c0L[ewr*8 + ewc] = cnA; c0L[ewr*8 + ewc + 1] = cnB;
        float hA = sigm(sr[24+ewc])  *tanh_(cnA);
        float hB = sigm(sr[24+ewc+1])*tanh_(cnB);
        unsigned pk = (unsigned)f2bf(hA) | ((unsigned)f2bf(hB) << 16);
        *(unsigned*)(h0buf + poff + hslice + (size_t)ewr*512 + ewc) = pk;
      }
      PUBLISH(2*t + 1);
    }

    // ===== F (deferred from step t-1): wait end-publish(t-1); out(t-1) =====
    if (t >= 1){
      WAITX(2*t);
      {
        const unsigned short* hr = h1buf + (size_t)((t-1)&1)*(BATCH*512) + (size_t)rowA*512 + kfo;
        #pragma unroll
        for (int ks = 0; ks < 16; ks++){
          h1f[ks] = *(const bfrag8*)(hr + ks*32);   // cache for this step's phase B
          oacc = mfma16(h1f[ks], BF(L_WOUT, 0, ks*32), oacc);
        }
      }
      if (l16 < 8){
        size_t ob = (size_t)(t-1)*(BATCH*512) + (size_t)(bg*64 + wave*16 + quad*4)*512 + wn*8 + l16;
        out[ob]        = oacc[0];
        out[ob + 512]  = oacc[1];
        out[ob + 1024] = oacc[2];
        out[ob + 1536] = oacc[3];
      }
    }

    if (t < T_STEPS){
      // ===== B (off critical path): gates1 partial = B1 + h1(t-1) @ W_hh1 =====
      float bbA = b1sl[l16], bbB = b1sl[16 + l16];
      f32x4 g1a = {bbA,bbA,bbA,bbA}, g1b = {bbB,bbB,bbB,bbB};
      if (t > 0){
        #pragma unroll
        for (int ks = 0; ks < 16; ks++){
          g1a = mfma16(h1f[ks], BF(L_WHH1, 0, ks*32), g1a);
          g1b = mfma16(h1f[ks], BF(L_WHH1, 1, ks*32), g1b);
        }
      }
      // ===== C (off critical path): x-part of gates0 for t+1 =====
      if (t < T_STEPS - 1){
        f32x4 z = {0.f,0.f,0.f,0.f};
        xacc0 = z; xacc1 = z;
        const unsigned short* xr = xb + ((size_t)(t+1)*BATCH + rowA)*512 + kfo;
        #pragma unroll
        for (int ks = 0; ks < 16; ks++){
          bfrag8 a = *(const bfrag8*)(xr + ks*32);
          xacc0 = mfma16(a, BF(L_WIH0, 0, ks*32), xacc0);
          xacc1 = mfma16(a, BF(L_WIH0, 1, ks*32), xacc1);
        }
      }
      // ===== wait phase-A publish of step t (h0' of whole batch at MALL) =====
      WAITX(2*t + 1);

      // ===== D+E: one pass over h0'(t): gates1 += h0'@Wc1 ; oacc = B2 + h0'@W2 =====
      float bo = (l16 < 8) ? b2sl[l16] : 0.f;
      oacc[0] = bo; oacc[1] = bo; oacc[2] = bo; oacc[3] = bo;
      {
        const unsigned short* hr = h0buf + poff + (size_t)rowA*512 + kfo;
        #pragma unroll
        for (int ks = 0; ks < 16; ks++){
          h0f[ks] = *(const bfrag8*)(hr + ks*32);   // cache for next step's phase A
          g1a  = mfma16(h0f[ks], BF(L_WC1, 0, ks*32), g1a);
          g1b  = mfma16(h0f[ks], BF(L_WC1, 1, ks*32), g1b);
          oacc = mfma16(h0f[ks], BF(L_W2,  0, ks*32), oacc);
        }
      }
      {   // stage + elementwise -> h1', c1
        const int rb2 = wave*16 + quad*4;
        #pragma unroll
        for (int r = 0; r < 4; r++){
          stg[(rb2+r)*33 + l16]      = g1a[r];
          stg[(rb2+r)*33 + 16 + l16] = g1b[r];
        }
        __syncthreads();
        const float* sr = stg + ewr*33;
        float cA = c1L[ewr*8 + ewc], cB = c1L[ewr*8 + ewc + 1];
        float cnA = sigm(sr[8+ewc])  *cA + sigm(sr[ewc])  *tanh_(sr[16+ewc]);
        float cnB = sigm(sr[8+ewc+1])*cB + sigm(sr[ewc+1])*tanh_(sr[16+ewc+1]);
        c1L[ewr*8 + ewc] = cnA; c1L[ewr*8 + ewc + 1] = cnB;
        float hA = sigm(sr[24+ewc])  *tanh_(cnA);
        float hB = sigm(sr[24+ewc+1])*tanh_(cnB);
        unsigned pk = (unsigned)f2bf(hA) | ((unsigned)f2bf(hB) << 16);
        *(unsigned*)(h1buf + poff + hslice + (size_t)ewr*512 + ewc) = pk;
      }
      PUBLISH(2*t + 2);
    }
  }
#undef BF
#undef PUBLISH
#undef WAITX
}

// ---------------- host (round-3 verbatim) ----------------
extern "C" void kernel_launch(void* const* d_in, const int* in_sizes, int n_in,
                              void* d_out, int out_size, void* d_ws, size_t ws_size,
                              hipStream_t stream){
  (void)in_sizes; (void)n_in; (void)out_size; (void)ws_size;
  const float* x    = (const float*)d_in[0];
  const float* wih0 = (const float*)d_in[1];
  const float* whh0 = (const float*)d_in[2];
  const float* wih1 = (const float*)d_in[3];
  const float* whh1 = (const float*)d_in[4];
  const float* bih1 = (const float*)d_in[5];
  const float* bhh1 = (const float*)d_in[6];
  const float* wout = (const float*)d_in[7];
  const float* bout = (const float*)d_in[8];

  char* ws = (char*)d_ws;
  size_t off = 0;
  auto alloc = [&](size_t bytes){ void* p = ws + off; off += (bytes + 255) & ~(size_t)255; return p; };
  unsigned short* xbf   = (unsigned short*)alloc(33554432);  // x bf16
  unsigned short* wih0b = (unsigned short*)alloc(2097152);
  unsigned short* whh0b = (unsigned short*)alloc(2097152);
  unsigned short* wc1b  = (unsigned short*)alloc(2097152);
  unsigned short* whh1b = (unsigned short*)alloc(2097152);
  unsigned short* w2b   = (unsigned short*)alloc(524288);
  unsigned short* woutb = (unsigned short*)alloc(524288);
  float* b1 = (float*)alloc(8192);
  float* b2 = (float*)alloc(2048);
  unsigned short* h0b = (unsigned short*)alloc(524288);
  unsigned short* h1b = (unsigned short*)alloc(524288);
  unsigned int* flags = (unsigned int*)alloc(2048);

  hipMemsetAsync(flags, 0, 2048, stream);
  cast_f32_bf16<<<16384, 256, 0, stream>>>(x, xbf, 16777216/4);
  cast_f32_bf16<<<1024, 256, 0, stream>>>(wih0, wih0b, 1048576/4);
  cast_f32_bf16<<<1024, 256, 0, stream>>>(whh0, whh0b, 1048576/4);
  cast_f32_bf16<<<1024, 256, 0, stream>>>(whh1, whh1b, 1048576/4);
  cast_f32_bf16<<<256,  256, 0, stream>>>(wout, woutb, 262144/4);
  gemm_combo<<<dim3(8,32), 256, 0, stream>>>(wih1, wout, wc1b, 2048, 512, 512);  // Wc1 = W_ih1 @ W_out
  gemm_combo<<<dim3(8,8),  256, 0, stream>>>(wout, wout, w2b,  512, 512, 512);   // W2  = W_out @ W_out
  bias_prep<<<10, 256, 0, stream>>>(wih1, bih1, bhh1, wout, bout, b1, b2);

  unsigned int* f1p = flags;
  unsigned int* f2p = flags + 256;
  float* outp = (float*)d_out;
  void* kargs[] = {
    (void*)&xbf, (void*)&wih0b, (void*)&whh0b, (void*)&wc1b, (void*)&whh1b,
    (void*)&w2b, (void*)&woutb, (void*)&b1, (void*)&b2,
    (void*)&h0b, (void*)&h1b, (void*)&f1p, (void*)&f2p, (void*)&outp
  };
  hipFuncSetAttribute((const void*)fflstm_persist,
                      hipFuncAttributeMaxDynamicSharedMemorySize, SMEM_BYTES);
  hipLaunchCooperativeKernel((const void*)fflstm_persist, dim3(256), dim3(256),
                             kargs, SMEM_BYTES, stream);
}

// Round 7
// 2148.594 us; speedup vs baseline: 1.5403x; 1.3714x over previous
//
#include <hip/hip_runtime.h>
#include <stdint.h>

#define T_STEPS 128
#define BATCH   256

typedef __attribute__((ext_vector_type(8))) short bfrag8;   // 8 x bf16
typedef __attribute__((ext_vector_type(4))) float f32x4;

// ---------------- LDS layout (persistent kernel) ----------------
#define L_WIH0 0
#define L_WHH0 16640
#define L_WC1  33280
#define L_WHH1 49920
#define L_W2   66560
#define L_WOUT 70720
#define L_STG_B 149760
#define L_C0_B  158208
#define L_C1_B  160256
#define L_B1_B  162304
#define L_B2_B  162432
#define SMEM_BYTES 162464

static __device__ __forceinline__ unsigned short f2bf(float f){
  union { float f; unsigned u; } v; v.f = f;
  return (unsigned short)((v.u + 0x7FFFu + ((v.u >> 16) & 1u)) >> 16);  // RNE
}
static __device__ __forceinline__ float sigm(float x){
  return 1.f / (1.f + __expf(-x));
}
static __device__ __forceinline__ float tanh_(float x){
  x = fminf(15.f, fmaxf(-15.f, x));
  float e = __expf(2.f * x);
  return 1.f - 2.f / (e + 1.f);
}
static __device__ __forceinline__ f32x4 mfma16(bfrag8 a, bfrag8 b, f32x4 c){
  return __builtin_amdgcn_mfma_f32_16x16x32_bf16(a, b, c, 0, 0, 0);
}

// Coherence-point fragment load (PROVEN correct in round 5): two relaxed
// AGENT-scope 64-bit atomic loads — compiler-emitted, bypasses stale L1/L2.
static __device__ __forceinline__ bfrag8 load_mall16(const unsigned short* p){
  union { unsigned long long u[2]; bfrag8 f; } cv;
  cv.u[0] = __hip_atomic_load((const unsigned long long*)p,
                              __ATOMIC_RELAXED, __HIP_MEMORY_SCOPE_AGENT);
  cv.u[1] = __hip_atomic_load((const unsigned long long*)(p + 4),
                              __ATOMIC_RELAXED, __HIP_MEMORY_SCOPE_AGENT);
  return cv.f;
}

// ---------------- prep kernels (proven, verbatim) ----------------
__global__ void cast_f32_bf16(const float* __restrict__ in, unsigned short* __restrict__ out, int n4){
  int i = blockIdx.x * blockDim.x + threadIdx.x;
  if (i < n4){
    float4 v = ((const float4*)in)[i];
    ushort4 o;
    o.x = f2bf(v.x); o.y = f2bf(v.y); o.z = f2bf(v.z); o.w = f2bf(v.w);
    ((ushort4*)out)[i] = o;
  }
}

__global__ void __launch_bounds__(256) gemm_combo(const float* __restrict__ A, const float* __restrict__ B,
                                                  unsigned short* __restrict__ C, int M, int N, int K){
  __shared__ float As[64][17];
  __shared__ float Bs[16][68];
  int col0 = blockIdx.x * 64;
  int row0 = blockIdx.y * 64;
  int tid = threadIdx.x;
  int tx = tid & 15, ty = tid >> 4;
  float acc[4][4] = {};
  for (int kp = 0; kp < K; kp += 16){
    for (int i = tid; i < 64*16; i += 256){
      int r = i >> 4, c = i & 15;
      As[r][c] = A[(size_t)(row0 + r) * K + kp + c];
    }
    for (int i = tid; i < 16*64; i += 256){
      int r = i >> 6, c = i & 63;
      Bs[r][c] = B[(size_t)(kp + r) * N + col0 + c];
    }
    __syncthreads();
    #pragma unroll
    for (int kk = 0; kk < 16; kk++){
      float a[4], b[4];
      #pragma unroll
      for (int i = 0; i < 4; i++) a[i] = As[ty*4 + i][kk];
      #pragma unroll
      for (int j = 0; j < 4; j++) b[j] = Bs[kk][tx*4 + j];
      #pragma unroll
      for (int i = 0; i < 4; i++)
        #pragma unroll
        for (int j = 0; j < 4; j++) acc[i][j] += a[i] * b[j];
    }
    __syncthreads();
  }
  for (int i = 0; i < 4; i++)
    for (int j = 0; j < 4; j++)
      C[(size_t)(row0 + ty*4 + i) * N + col0 + tx*4 + j] = f2bf(acc[i][j]);
}

__global__ void bias_prep(const float* __restrict__ wih1, const float* __restrict__ bih,
                          const float* __restrict__ bhh, const float* __restrict__ wout,
                          const float* __restrict__ bout, float* __restrict__ B1, float* __restrict__ B2){
  int t = blockIdx.x * blockDim.x + threadIdx.x;
  if (t < 2048){
    float s = bih[t] + bhh[t];
    for (int k = 0; k < 512; k++) s += wih1[(size_t)t*512 + k] * bout[k];
    B1[t] = s;
  } else if (t < 2560){
    int n = t - 2048;
    float s = bout[n];
    for (int k = 0; k < 512; k++) s += wout[(size_t)n*512 + k] * bout[k];
    B2[n] = s;
  }
}

// ---------------- persistent recurrence kernel ----------------
// Base: round-3-proven (2876µs) structure. Changes this round:
//  1. h-state exchange is FULLY ATOMIC: producer h stores are relaxed AGENT
//     atomic b32 (flow through to MALL, never dirty in L2); consumer h reads
//     are round-5-PROVEN relaxed AGENT atomic loads, now BATCHED (all 16
//     frags issued before the MFMAs -> one MALL latency, not 16).
//  2. ALL four per-step fences deleted (no wbl2, no inv, no election).
//     Ordering: data atomic stores -> s_waitcnt(0) (acks from coherence
//     point) -> syncthreads -> relaxed flag store.  [tests ack semantics]
//  3. c0L/c1L transposed to [col*64+row]: bank = lane%32, removes the
//     16-way LDS conflict (was the bulk of SQ_LDS_BANK_CONFLICT=1.0e8).
__global__ void __launch_bounds__(256, 1) fflstm_persist(
    const unsigned short* __restrict__ xb,     // [T][256][512] bf16
    const unsigned short* __restrict__ wih0g,
    const unsigned short* __restrict__ whh0g,
    const unsigned short* __restrict__ wc1g,   // W_ih1 @ W_out
    const unsigned short* __restrict__ whh1g,
    const unsigned short* __restrict__ w2g,    // W_out @ W_out
    const unsigned short* __restrict__ woutg,
    const float* __restrict__ b1g,
    const float* __restrict__ b2g,
    unsigned short* __restrict__ h0buf,        // [2][256][512] bf16 parity buffers
    unsigned short* __restrict__ h1buf,
    unsigned int* flags1,                      // [256]
    unsigned int* flags2,
    float* __restrict__ out)                   // [T][256][512] fp32
{
  extern __shared__ char smem[];
  unsigned short* wl = (unsigned short*)smem;
  float* stg  = (float*)(smem + L_STG_B);
  float* c0L  = (float*)(smem + L_C0_B);
  float* c1L  = (float*)(smem + L_C1_B);
  float* b1sl = (float*)(smem + L_B1_B);
  float* b2sl = (float*)(smem + L_B2_B);

  const int wg = blockIdx.x;
  const int bg = wg >> 6;        // batch group (64 rows each)
  const int wn = wg & 63;        // column-slice: 8 h-cols, 32 gate-cols
  const int tid = threadIdx.x;
  const int wave = tid >> 6;
  const int lane = tid & 63;
  const int quad = lane >> 4;
  const int l16  = lane & 15;

  // ---- stage weight slices into LDS (rows packed [i(8) f(8) g(8) o(8)]) ----
  {
    const unsigned short* gsrc[4] = { wih0g, whh0g, wc1g, whh1g };
    #pragma unroll
    for (int m = 0; m < 4; m++){
      unsigned short* dst = wl + m * 16640;
      const unsigned short* src = gsrc[m];
      for (int i = tid; i < 32*512; i += 256){
        int s = i >> 9, k = i & 511;
        int gr = ((s >> 3) << 9) + wn*8 + (s & 7);
        dst[s*520 + k] = src[(size_t)gr*512 + k];
      }
    }
    const unsigned short* osrc[2] = { w2g, woutg };
    #pragma unroll
    for (int m = 0; m < 2; m++){
      unsigned short* dst = wl + L_W2 + m * 4160;
      const unsigned short* src = osrc[m];
      for (int i = tid; i < 8*512; i += 256){
        int s = i >> 9, k = i & 511;
        dst[s*520 + k] = src[(size_t)(wn*8 + s)*512 + k];
      }
    }
  }
  if (tid < 32) b1sl[tid] = b1g[((tid >> 3) << 9) + wn*8 + (tid & 7)];
  if (tid < 8)  b2sl[tid] = b2g[wn*8 + tid];
  for (int i = tid; i < 512; i += 256){ c0L[i] = 0.f; c1L[i] = 0.f; }
  __syncthreads();

  const int rowA = bg*64 + wave*16 + l16;   // A-fragment row for this lane
  const int kfo  = quad*8;                  // A/B fragment k offset

#define BF(base, nt, k0) (*(const bfrag8*)&wl[(base) + ((nt)*16 + l16)*520 + (k0) + kfo])

  // prologue: x-part of gates0 for t=0
  f32x4 xacc0 = {0.f,0.f,0.f,0.f}, xacc1 = {0.f,0.f,0.f,0.f};
  {
    const unsigned short* xr = xb + (size_t)rowA*512 + kfo;
    #pragma unroll
    for (int ks = 0; ks < 16; ks++){
      bfrag8 a = *(const bfrag8*)(xr + ks*32);
      xacc0 = mfma16(a, BF(L_WIH0, 0, ks*32), xacc0);
      xacc1 = mfma16(a, BF(L_WIH0, 1, ks*32), xacc1);
    }
  }

  bfrag8 h0f[16], h1f[16];   // register-cached activation fragments
  f32x4 oacc = {0.f,0.f,0.f,0.f};   // loop-carried: out-partial of step t-1
  const int ewr = tid & 63;
  const int ewc = (tid >> 6) * 2;
  const size_t hslice = (size_t)(bg*64)*512 + wn*8;

  for (int t = 0; t <= T_STEPS; t++){
    const int par = t & 1;
    const size_t poff = (size_t)par * (BATCH*512);

    // ===== A: gates0 = xacc + h0(t-1) @ W_hh0 (h0 frags cached in regs) =====
    if (t < T_STEPS){
      f32x4 g0a = xacc0, g0b = xacc1;
      if (t > 0){
        #pragma unroll
        for (int ks = 0; ks < 16; ks++){
          g0a = mfma16(h0f[ks], BF(L_WHH0, 0, ks*32), g0a);
          g0b = mfma16(h0f[ks], BF(L_WHH0, 1, ks*32), g0b);
        }
      }
      {   // stage [64x32] + LSTM elementwise -> h0' (atomic b32 to MALL), c0 (LDS)
        const int rb2 = wave*16 + quad*4;
        #pragma unroll
        for (int r = 0; r < 4; r++){
          stg[(rb2+r)*33 + l16]      = g0a[r];
          stg[(rb2+r)*33 + 16 + l16] = g0b[r];
        }
        __syncthreads();
        const float* sr = stg + ewr*33;
        float cA = c0L[ewc*64 + ewr], cB = c0L[(ewc+1)*64 + ewr];   // conflict-free layout
        float cnA = sigm(sr[8+ewc])  *cA + sigm(sr[ewc])  *tanh_(sr[16+ewc]);
        float cnB = sigm(sr[8+ewc+1])*cB + sigm(sr[ewc+1])*tanh_(sr[16+ewc+1]);
        c0L[ewc*64 + ewr] = cnA; c0L[(ewc+1)*64 + ewr] = cnB;
        float hA = sigm(sr[24+ewc])  *tanh_(cnA);
        float hB = sigm(sr[24+ewc+1])*tanh_(cnB);
        unsigned pk = (unsigned)f2bf(hA) | ((unsigned)f2bf(hB) << 16);
        __hip_atomic_store((unsigned*)(h0buf + poff + hslice + (size_t)ewr*512 + ewc),
                           pk, __ATOMIC_RELAXED, __HIP_MEMORY_SCOPE_AGENT);
      }
      __builtin_amdgcn_s_waitcnt(0);   // atomic stores acked at coherence point
      __syncthreads();
      if (tid == 0){
        __hip_atomic_store(&flags1[wg], (unsigned)(t+1), __ATOMIC_RELAXED, __HIP_MEMORY_SCOPE_AGENT);
      }
    }

    // ===== F (deferred from step t-1): wait flag2; out(t-1) = oacc + h1'(t-1)@Wout =====
    if (t >= 1){
      if (tid < 64){
        int spins = 0;
        while (__hip_atomic_load(&flags2[bg*64 + tid], __ATOMIC_RELAXED, __HIP_MEMORY_SCOPE_AGENT) < (unsigned)t){
          __builtin_amdgcn_s_sleep(1);
          if (++spins > (1 << 20)) break;
        }
      }
      __syncthreads();
      __builtin_amdgcn_sched_barrier(0);       // no hoisting of loads above spin
      {
        const unsigned short* hr = h1buf + (size_t)((t-1)&1)*(BATCH*512) + (size_t)rowA*512 + kfo;
        #pragma unroll
        for (int ks = 0; ks < 16; ks++)
          h1f[ks] = load_mall16(hr + ks*32);   // batched: one MALL latency for all
        #pragma unroll
        for (int ks = 0; ks < 16; ks++)
          oacc = mfma16(h1f[ks], BF(L_WOUT, 0, ks*32), oacc);
      }
      if (l16 < 8){
        size_t ob = (size_t)(t-1)*(BATCH*512) + (size_t)(bg*64 + wave*16 + quad*4)*512 + wn*8 + l16;
        out[ob]        = oacc[0];
        out[ob + 512]  = oacc[1];
        out[ob + 1024] = oacc[2];
        out[ob + 1536] = oacc[3];
      }
    }

    if (t < T_STEPS){
      // ===== B (off critical path): gates1 partial = B1 + h1(t-1) @ W_hh1 =====
      float bbA = b1sl[l16], bbB = b1sl[16 + l16];
      f32x4 g1a = {bbA,bbA,bbA,bbA}, g1b = {bbB,bbB,bbB,bbB};
      if (t > 0){
        #pragma unroll
        for (int ks = 0; ks < 16; ks++){
          g1a = mfma16(h1f[ks], BF(L_WHH1, 0, ks*32), g1a);
          g1b = mfma16(h1f[ks], BF(L_WHH1, 1, ks*32), g1b);
        }
      }
      // ===== C (off critical path): x-part of gates0 for t+1 =====
      if (t < T_STEPS - 1){
        f32x4 z = {0.f,0.f,0.f,0.f};
        xacc0 = z; xacc1 = z;
        const unsigned short* xr = xb + ((size_t)(t+1)*BATCH + rowA)*512 + kfo;
        #pragma unroll
        for (int ks = 0; ks < 16; ks++){
          bfrag8 a = *(const bfrag8*)(xr + ks*32);
          xacc0 = mfma16(a, BF(L_WIH0, 0, ks*32), xacc0);
          xacc1 = mfma16(a, BF(L_WIH0, 1, ks*32), xacc1);
        }
      }
      // ===== wait flag1 (h0' of whole batch-group at MALL) =====
      if (tid < 64){
        int spins = 0;
        while (__hip_atomic_load(&flags1[bg*64 + tid], __ATOMIC_RELAXED, __HIP_MEMORY_SCOPE_AGENT) < (unsigned)(t+1)){
          __builtin_amdgcn_s_sleep(1);
          if (++spins > (1 << 20)) break;   // hang safety
        }
      }
      __syncthreads();
      __builtin_amdgcn_sched_barrier(0);

      // ===== D+E: one pass over h0'(t): gates1 += h0'@Wc1 ; oacc = B2 + h0'@W2 =====
      float bo = (l16 < 8) ? b2sl[l16] : 0.f;
      oacc[0] = bo; oacc[1] = bo; oacc[2] = bo; oacc[3] = bo;
      {
        const unsigned short* hr = h0buf + poff + (size_t)rowA*512 + kfo;
        #pragma unroll
        for (int ks = 0; ks < 16; ks++)
          h0f[ks] = load_mall16(hr + ks*32);   // batched; cached for next phase A
        #pragma unroll
        for (int ks = 0; ks < 16; ks++){
          g1a  = mfma16(h0f[ks], BF(L_WC1, 0, ks*32), g1a);
          g1b  = mfma16(h0f[ks], BF(L_WC1, 1, ks*32), g1b);
          oacc = mfma16(h0f[ks], BF(L_W2,  0, ks*32), oacc);
        }
      }
      {   // stage + elementwise -> h1' (atomic b32), c1 (LDS)
        const int rb2 = wave*16 + quad*4;
        #pragma unroll
        for (int r = 0; r < 4; r++){
          stg[(rb2+r)*33 + l16]      = g1a[r];
          stg[(rb2+r)*33 + 16 + l16] = g1b[r];
        }
        __syncthreads();
        const float* sr = stg + ewr*33;
        float cA = c1L[ewc*64 + ewr], cB = c1L[(ewc+1)*64 + ewr];
        float cnA = sigm(sr[8+ewc])  *cA + sigm(sr[ewc])  *tanh_(sr[16+ewc]);
        float cnB = sigm(sr[8+ewc+1])*cB + sigm(sr[ewc+1])*tanh_(sr[16+ewc+1]);
        c1L[ewc*64 + ewr] = cnA; c1L[(ewc+1)*64 + ewr] = cnB;
        float hA = sigm(sr[24+ewc])  *tanh_(cnA);
        float hB = sigm(sr[24+ewc+1])*tanh_(cnB);
        unsigned pk = (unsigned)f2bf(hA) | ((unsigned)f2bf(hB) << 16);
        __hip_atomic_store((unsigned*)(h1buf + poff + hslice + (size_t)ewr*512 + ewc),
                           pk, __ATOMIC_RELAXED, __HIP_MEMORY_SCOPE_AGENT);
      }
      __builtin_amdgcn_s_waitcnt(0);   // atomic stores acked at coherence point
      __syncthreads();
      if (tid == 0){
        __hip_atomic_store(&flags2[wg], (unsigned)(t+1), __ATOMIC_RELAXED, __HIP_MEMORY_SCOPE_AGENT);
      }
    }
  }
#undef BF
}

// ---------------- host (round-3 verbatim) ----------------
extern "C" void kernel_launch(void* const* d_in, const int* in_sizes, int n_in,
                              void* d_out, int out_size, void* d_ws, size_t ws_size,
                              hipStream_t stream){
  (void)in_sizes; (void)n_in; (void)out_size; (void)ws_size;
  const float* x    = (const float*)d_in[0];
  const float* wih0 = (const float*)d_in[1];
  const float* whh0 = (const float*)d_in[2];
  const float* wih1 = (const float*)d_in[3];
  const float* whh1 = (const float*)d_in[4];
  const float* bih1 = (const float*)d_in[5];
  const float* bhh1 = (const float*)d_in[6];
  const float* wout = (const float*)d_in[7];
  const float* bout = (const float*)d_in[8];

  char* ws = (char*)d_ws;
  size_t off = 0;
  auto alloc = [&](size_t bytes){ void* p = ws + off; off += (bytes + 255) & ~(size_t)255; return p; };
  unsigned short* xbf   = (unsigned short*)alloc(33554432);  // x bf16
  unsigned short* wih0b = (unsigned short*)alloc(2097152);
  unsigned short* whh0b = (unsigned short*)alloc(2097152);
  unsigned short* wc1b  = (unsigned short*)alloc(2097152);
  unsigned short* whh1b = (unsigned short*)alloc(2097152);
  unsigned short* w2b   = (unsigned short*)alloc(524288);
  unsigned short* woutb = (unsigned short*)alloc(524288);
  float* b1 = (float*)alloc(8192);
  float* b2 = (float*)alloc(2048);
  unsigned short* h0b = (unsigned short*)alloc(524288);
  unsigned short* h1b = (unsigned short*)alloc(524288);
  unsigned int* flags = (unsigned int*)alloc(2048);

  hipMemsetAsync(flags, 0, 2048, stream);
  cast_f32_bf16<<<16384, 256, 0, stream>>>(x, xbf, 16777216/4);
  cast_f32_bf16<<<1024, 256, 0, stream>>>(wih0, wih0b, 1048576/4);
  cast_f32_bf16<<<1024, 256, 0, stream>>>(whh0, whh0b, 1048576/4);
  cast_f32_bf16<<<1024, 256, 0, stream>>>(whh1, whh1b, 1048576/4);
  cast_f32_bf16<<<256,  256, 0, stream>>>(wout, woutb, 262144/4);
  gemm_combo<<<dim3(8,32), 256, 0, stream>>>(wih1, wout, wc1b, 2048, 512, 512);  // Wc1 = W_ih1 @ W_out
  gemm_combo<<<dim3(8,8),  256, 0, stream>>>(wout, wout, w2b,  512, 512, 512);   // W2  = W_out @ W_out
  bias_prep<<<10, 256, 0, stream>>>(wih1, bih1, bhh1, wout, bout, b1, b2);

  unsigned int* f1p = flags;
  unsigned int* f2p = flags + 256;
  float* outp = (float*)d_out;
  void* kargs[] = {
    (void*)&xbf, (void*)&wih0b, (void*)&whh0b, (void*)&wc1b, (void*)&whh1b,
    (void*)&w2b, (void*)&woutb, (void*)&b1, (void*)&b2,
    (void*)&h0b, (void*)&h1b, (void*)&f1p, (void*)&f2p, (void*)&outp
  };
  hipFuncSetAttribute((const void*)fflstm_persist,
                      hipFuncAttributeMaxDynamicSharedMemorySize, SMEM_BYTES);
  hipLaunchCooperativeKernel((const void*)fflstm_persist, dim3(256), dim3(256),
                             kargs, SMEM_BYTES, stream);
}